// Round 16
// baseline (92.735 us; speedup 1.0000x reference)
//
#include <hip/hip_runtime.h>

typedef float v4f __attribute__((ext_vector_type(4)));
typedef short v8s __attribute__((ext_vector_type(8)));

#define BM 128

__device__ __forceinline__ unsigned short f2bf(float f) {
    union { float f; unsigned u; } v; v.f = f;
    unsigned u = v.u;
    u += 0x7FFFu + ((u >> 16) & 1u);   // round-to-nearest-even
    return (unsigned short)(u >> 16);
}

// pack two f32 -> two bf16 (RNE) in one instruction
__device__ __forceinline__ unsigned cvt_pk_bf16(float lo, float hi) {
    unsigned r;
    asm("v_cvt_pk_bf16_f32 %0, %1, %2" : "=v"(r) : "v"(lo), "v"(hi));
    return r;
}

// shared-LDS sync WITHOUT draining vmcnt: only lgkm (ds ops) must complete;
// in-flight global loads into registers survive the barrier.
#define LDS_BARRIER() do {                                        \
    asm volatile("s_waitcnt lgkmcnt(0)" ::: "memory");            \
    __builtin_amdgcn_s_barrier();                                 \
    __builtin_amdgcn_sched_barrier(0);                            \
} while (0)

#define SB() __builtin_amdgcn_sched_barrier(0)

__device__ __forceinline__ float fast_exp2(float x) {
#if __has_builtin(__builtin_amdgcn_exp2f)
    return __builtin_amdgcn_exp2f(x);
#else
    return exp2f(x);
#endif
}
__device__ __forceinline__ float fast_rcp(float x) {
#if __has_builtin(__builtin_amdgcn_rcpf)
    return __builtin_amdgcn_rcpf(x);
#else
    return 1.0f / x;
#endif
}
__device__ __forceinline__ float fast_tanh(float y) {
    float t = fast_exp2(y * 2.885390081777927f);
    return (t - 1.0f) * fast_rcp(t + 1.0f);
}
__device__ __forceinline__ float fast_sigmoid(float z) {
    float t = fast_exp2(-1.4426950408889634f * z);
    return fast_rcp(1.0f + t);
}

// ---------------------------------------------------------------------------
// Pack 5 weight matrices (fp32 row-major [N][K]) into bf16 MFMA-B-fragment
// order (canonical 16x32 tile: lane = ((k>>3)&3)*16 + (n&15), j = k&7).
// ws layout: Wb(98304) | W1(65536) | W2 | Wa | Wt   (bf16 elems)
// ---------------------------------------------------------------------------
__global__ void prep_pack(const float* __restrict__ Wb, const float* __restrict__ W1,
                          const float* __restrict__ W2, const float* __restrict__ Wa,
                          const float* __restrict__ Wt, unsigned short* __restrict__ ws)
{
    int e = blockIdx.x * 256 + threadIdx.x;
    if (e >= 360448) return;
    const float* src; int K; int base;
    if (e < 98304)       { src = Wb; K = 384; base = 0; }
    else if (e < 163840) { src = W1; K = 256; base = 98304; }
    else if (e < 229376) { src = W2; K = 256; base = 163840; }
    else if (e < 294912) { src = Wa; K = 256; base = 229376; }
    else                 { src = Wt; K = 256; base = 294912; }
    int le   = e - base;
    int j    = le & 7;
    int lane = (le >> 3) & 63;
    int tile = le >> 9;
    int kt   = K >> 5;
    int ks   = tile % kt;
    int nt   = tile / kt;
    int n = nt * 16 + (lane & 15);
    int k = ks * 32 + (lane >> 4) * 8 + j;
    ws[e] = f2bf(src[n * K + k]);
}

// ---------------------------------------------------------------------------
// Fused CfC cell, BM=128 rows/block, 4 waves each owning 64 output cols.
// Phase 1 runs as TWO half-passes of 64 rows (C-slice = 64 AGPR each, halves
// SSA-disjoint); phase 2 uses the full C[4][8] (128 AGPR): each 1KB B-load
// feeds 32 MFMAs (8 row-tiles x 4 mats) -- 2x the MFMA:fetch ratio of BM=64.
// Weights: global->3-deep VGPR rotation br0/br1/br2, issue-ahead-2, compiler
// waitcnt. X = 64KB LDS; each half's input chunks overlay that half's own X
// region (written only after consumption). Grid 512 = exactly 2 blocks/CU,
// one round. Flat 56 steps: 0..23 phase 1 (2 halves x 6 chunks x 2), 24..55
// phase 2 (4 g x 8 ks).
// ---------------------------------------------------------------------------
__global__ __launch_bounds__(256, 2) void cfc_fused(
    const float* __restrict__ xin, const float* __restrict__ hx,
    const float* __restrict__ ts,
    const float* __restrict__ bb, const float* __restrict__ b1,
    const float* __restrict__ b2, const float* __restrict__ ba,
    const float* __restrict__ bt,
    const unsigned short* __restrict__ wpk,
    float* __restrict__ out)
{
    __shared__ unsigned short lds[32768];   // 64 KB: X tiles (mt2,ks) 8x8 x 1KB
    const int tid  = threadIdx.x;
    const int lane = tid & 63;
    const int w    = tid >> 6;        // wave id = output-col group (64 cols)
    const int row0 = blockIdx.x * BM;

    v8s br0[4], br1[4], br2[4];       // 3-deep B rotation (48 VGPR)
    v4f C[4][8];                      // unified accumulator (128 AGPR in ph2)

// load step-S weight tile (4 x 16B/lane, coalesced) into DST regs
#define BLOAD(S, DST) do {                                                    \
    _Pragma("unroll")                                                         \
    for (int i = 0; i < 4; ++i) {                                             \
        size_t goff;                                                          \
        if ((S) < 24) {                                                       \
            goff = (size_t)((w * 4 + i) * 12 + ((S) % 12)) * 512;             \
        } else {                                                              \
            int s2_ = (S) - 24, g_ = s2_ >> 3, ks_ = s2_ & 7;                 \
            goff = 98304u + (size_t)i * 65536                                 \
                 + (size_t)((w * 4 + g_) * 8 + ks_) * 512;                    \
        }                                                                     \
        DST[i] = *reinterpret_cast<const v8s*>(wpk + goff + (size_t)lane * 8);\
    }                                                                         \
} while (0)

// 64-row x 64-col input chunk: 1024 v4f, 4 per thread
#define ISSUE_IN(SRC, LD, BUF) do {                                           \
    _Pragma("unroll")                                                         \
    for (int it = 0; it < 4; ++it) {                                          \
        int i_ = tid + it * 256; int r_ = i_ >> 4; int c4_ = i_ & 15;         \
        BUF[it] = *(reinterpret_cast<const v4f*>((SRC) + (size_t)r_ * (LD)) + c4_); \
    }                                                                         \
} while (0)

#define WRITE_IN(BUF, CB) do {                                                \
    _Pragma("unroll")                                                         \
    for (int it = 0; it < 4; ++it) {                                          \
        int i_ = tid + it * 256; int r_ = i_ >> 4; int c4_ = i_ & 15;         \
        uint2 pk_;                                                            \
        pk_.x = cvt_pk_bf16(BUF[it][0], BUF[it][1]);                          \
        pk_.y = cvt_pk_bf16(BUF[it][2], BUF[it][3]);                          \
        int idx_ = (((r_ >> 4) * 2 + (c4_ >> 3)) * 64 + ((c4_ >> 1) & 3) * 16 \
                    + (r_ & 15)) * 8 + (c4_ & 1) * 4;                         \
        *reinterpret_cast<uint2*>(&lds[(CB) + idx_]) = pk_;                   \
    }                                                                         \
} while (0)

// accumulator init for half H (bias bb broadcast)
#define ACCINIT(H) do {                                                       \
    _Pragma("unroll")                                                         \
    for (int nt = 0; nt < 4; ++nt) {                                          \
        float bv_ = bb[w * 64 + nt * 16 + (lane & 15)];                       \
        v4f bq_ = {bv_, bv_, bv_, bv_};                                       \
        _Pragma("unroll")                                                     \
        for (int mt = 0; mt < 4; ++mt) C[nt][(H)*4 + mt] = bq_;               \
    }                                                                         \
} while (0)

// phase-1 step (half H): A from chunk LDS at CB=H*16384, B from CUR regs
#define P1STEP(S, H, CUR, PRE) do {                                           \
    BLOAD((S) + 2, PRE);                                                      \
    v8s aa_[4];                                                               \
    _Pragma("unroll")                                                         \
    for (int mt = 0; mt < 4; ++mt)                                            \
        aa_[mt] = *reinterpret_cast<const v8s*>(                              \
                      &lds[(H)*16384 + ((mt * 2 + ((S) & 1)) * 64 + lane) * 8]); \
    __builtin_amdgcn_s_setprio(1);                                            \
    _Pragma("unroll")                                                         \
    for (int nt = 0; nt < 4; ++nt)                                            \
        _Pragma("unroll")                                                     \
        for (int mt = 0; mt < 4; ++mt)                                        \
            C[nt][(H)*4 + mt] = __builtin_amdgcn_mfma_f32_16x16x32_bf16(      \
                              aa_[mt], CUR[nt], C[nt][(H)*4 + mt], 0, 0, 0);  \
    __builtin_amdgcn_s_setprio(0);                                            \
    SB();                                                                     \
} while (0)

// activation for half H: C[nt][H*4+mt] -> X tiles mt2 = H*4+mt
#define ACTIVATE(H) do {                                                      \
    _Pragma("unroll")                                                         \
    for (int nt = 0; nt < 4; ++nt)                                            \
        _Pragma("unroll")                                                     \
        for (int mt = 0; mt < 4; ++mt)                                        \
            _Pragma("unroll")                                                 \
            for (int r = 0; r < 4; ++r) {                                     \
                float xv_ = 1.7159f * fast_tanh(0.666f * C[nt][(H)*4+mt][r]); \
                int idx_ = ((((H)*4+mt)*8 + w*2 + (nt >> 1)) * 64             \
                           + ((nt & 1)*2 + ((lane >> 3) & 1)) * 16            \
                           + (lane >> 4)*4 + r) * 8 + (lane & 7);             \
                lds[idx_] = f2bf(xv_);                                        \
            }                                                                 \
} while (0)

// phase-2 step: 8 row-tiles, A-reads split in halves so the 2nd half's LDS
// latency hides under the 1st MFMA cluster; B (CUR) feeds all 32 MFMAs.
#define P2BODY(KS, CUR) do {                                                  \
    v8s aa_[4];                                                               \
    _Pragma("unroll")                                                         \
    for (int mt = 0; mt < 4; ++mt)                                            \
        aa_[mt] = *reinterpret_cast<const v8s*>(                              \
                      &lds[((mt * 8 + (KS)) * 64 + lane) * 8]);               \
    __builtin_amdgcn_s_setprio(1);                                            \
    _Pragma("unroll")                                                         \
    for (int mat = 0; mat < 4; ++mat)                                         \
        _Pragma("unroll")                                                     \
        for (int mt = 0; mt < 4; ++mt)                                        \
            C[mat][mt] = __builtin_amdgcn_mfma_f32_16x16x32_bf16(             \
                              aa_[mt], CUR[mat], C[mat][mt], 0, 0, 0);        \
    __builtin_amdgcn_s_setprio(0);                                            \
    v8s ab_[4];                                                               \
    _Pragma("unroll")                                                         \
    for (int mt = 0; mt < 4; ++mt)                                            \
        ab_[mt] = *reinterpret_cast<const v8s*>(                              \
                      &lds[(((mt + 4) * 8 + (KS)) * 64 + lane) * 8]);         \
    __builtin_amdgcn_s_setprio(1);                                            \
    _Pragma("unroll")                                                         \
    for (int mat = 0; mat < 4; ++mat)                                         \
        _Pragma("unroll")                                                     \
        for (int mt = 0; mt < 4; ++mt)                                        \
            C[mat][4 + mt] = __builtin_amdgcn_mfma_f32_16x16x32_bf16(         \
                              ab_[mt], CUR[mat], C[mat][4 + mt], 0, 0, 0);    \
    __builtin_amdgcn_s_setprio(0);                                            \
    SB();                                                                     \
} while (0)

#define P2STEP(S, KS, CUR, PRE) do { BLOAD((S) + 2, PRE); P2BODY(KS, CUR); } while (0)
#define P2STEP_NS(S, KS, CUR)   do { P2BODY(KS, CUR); } while (0)

#define GINIT(G) do {                                                         \
    const int n_ = w * 64 + (G) * 16 + (lane & 15);                           \
    float v1_ = b1[n_], v2_ = b2[n_], va_ = ba[n_], vt_ = bt[n_];             \
    v4f q1_ = {v1_,v1_,v1_,v1_}, q2_ = {v2_,v2_,v2_,v2_};                     \
    v4f qa_ = {va_,va_,va_,va_}, qt_ = {vt_,vt_,vt_,vt_};                     \
    _Pragma("unroll")                                                         \
    for (int mt = 0; mt < 8; ++mt) {                                          \
        C[0][mt] = q1_; C[1][mt] = q2_; C[2][mt] = qa_; C[3][mt] = qt_;       \
    }                                                                         \
} while (0)

#define EPI(G) do {                                                           \
    const int n_ = w * 64 + (G) * 16 + (lane & 15);                           \
    _Pragma("unroll")                                                         \
    for (int mt = 0; mt < 8; ++mt) {                                          \
        int rowb_ = row0 + mt * 16 + ((lane >> 4) << 2);                      \
        v4f tsv_ = *reinterpret_cast<const v4f*>(&ts[rowb_]);                 \
        _Pragma("unroll")                                                     \
        for (int r = 0; r < 4; ++r) {                                         \
            float ff1_ = fast_tanh(C[0][mt][r]);                              \
            float ff2_ = fast_tanh(C[1][mt][r]);                              \
            float ti_  = fast_sigmoid(C[2][mt][r] * tsv_[r] + C[3][mt][r]);   \
            out[(size_t)(rowb_ + r) * 256 + n_] = ff1_ + ti_ * (ff2_ - ff1_); \
        }                                                                     \
    }                                                                         \
} while (0)

    v4f sA[4], sB[4];
    const size_t r0 = (size_t)row0, r1 = (size_t)row0 + 64;

    // ---------------- phase 1, half 0 (rows row0..row0+63) ------------------
    ISSUE_IN(xin + r0 * 128, 128, sA);
    BLOAD(0, br0); BLOAD(1, br1);
    ACCINIT(0);
    WRITE_IN(sA, 0);
    ISSUE_IN(xin + r0 * 128 + 64, 128, sB);
    LDS_BARRIER();
    P1STEP(0,0, br0, br2); P1STEP(1,0, br1, br0);
    LDS_BARRIER();
    WRITE_IN(sB, 0); ISSUE_IN(hx + r0 * 256, 256, sA);
    LDS_BARRIER();
    P1STEP(2,0, br2, br1); P1STEP(3,0, br0, br2);
    LDS_BARRIER();
    WRITE_IN(sA, 0); ISSUE_IN(hx + r0 * 256 + 64, 256, sB);
    LDS_BARRIER();
    P1STEP(4,0, br1, br0); P1STEP(5,0, br2, br1);
    LDS_BARRIER();
    WRITE_IN(sB, 0); ISSUE_IN(hx + r0 * 256 + 128, 256, sA);
    LDS_BARRIER();
    P1STEP(6,0, br0, br2); P1STEP(7,0, br1, br0);
    LDS_BARRIER();
    WRITE_IN(sA, 0); ISSUE_IN(hx + r0 * 256 + 192, 256, sB);
    LDS_BARRIER();
    P1STEP(8,0, br2, br1); P1STEP(9,0, br0, br2);
    LDS_BARRIER();
    WRITE_IN(sB, 0); ISSUE_IN(xin + r1 * 128, 128, sA);     // half-1 chunk 0
    LDS_BARRIER();
    P1STEP(10,0, br1, br0); P1STEP(11,0, br2, br1);
    LDS_BARRIER();                  // all waves done reading half-0 chunks
    ACTIVATE(0);                    // C[.][0..3] -> X[0,16K) elems
    ACCINIT(1);
    WRITE_IN(sA, 16384); ISSUE_IN(xin + r1 * 128 + 64, 128, sB);
    LDS_BARRIER();

    // ---------------- phase 1, half 1 (rows row0+64..row0+127) --------------
    P1STEP(12,1, br0, br2); P1STEP(13,1, br1, br0);
    LDS_BARRIER();
    WRITE_IN(sB, 16384); ISSUE_IN(hx + r1 * 256, 256, sA);
    LDS_BARRIER();
    P1STEP(14,1, br2, br1); P1STEP(15,1, br0, br2);
    LDS_BARRIER();
    WRITE_IN(sA, 16384); ISSUE_IN(hx + r1 * 256 + 64, 256, sB);
    LDS_BARRIER();
    P1STEP(16,1, br1, br0); P1STEP(17,1, br2, br1);
    LDS_BARRIER();
    WRITE_IN(sB, 16384); ISSUE_IN(hx + r1 * 256 + 128, 256, sA);
    LDS_BARRIER();
    P1STEP(18,1, br0, br2); P1STEP(19,1, br1, br0);
    LDS_BARRIER();
    WRITE_IN(sA, 16384); ISSUE_IN(hx + r1 * 256 + 192, 256, sB);
    LDS_BARRIER();
    P1STEP(20,1, br2, br1); P1STEP(21,1, br0, br2);
    LDS_BARRIER();
    WRITE_IN(sB, 16384);
    LDS_BARRIER();
    P1STEP(22,1, br1, br0); P1STEP(23,1, br2, br1);
    LDS_BARRIER();                  // all waves done reading half-1 chunks
    ACTIVATE(1);                    // C[.][4..7] -> X[16K,32K) elems
    LDS_BARRIER();                  // X fully visible

    // ---------------- phase 2: 4 GEMMs over X + fused epilogue --------------
    GINIT(0);
    P2STEP(24,0, br0, br2); P2STEP(25,1, br1, br0);
    P2STEP(26,2, br2, br1); P2STEP(27,3, br0, br2);
    P2STEP(28,4, br1, br0); P2STEP(29,5, br2, br1);
    P2STEP(30,6, br0, br2); P2STEP(31,7, br1, br0);
    EPI(0);
    GINIT(1);
    P2STEP(32,0, br2, br1); P2STEP(33,1, br0, br2);
    P2STEP(34,2, br1, br0); P2STEP(35,3, br2, br1);
    P2STEP(36,4, br0, br2); P2STEP(37,5, br1, br0);
    P2STEP(38,6, br2, br1); P2STEP(39,7, br0, br2);
    EPI(1);
    GINIT(2);
    P2STEP(40,0, br1, br0); P2STEP(41,1, br2, br1);
    P2STEP(42,2, br0, br2); P2STEP(43,3, br1, br0);
    P2STEP(44,4, br2, br1); P2STEP(45,5, br0, br2);
    P2STEP(46,6, br1, br0); P2STEP(47,7, br2, br1);
    EPI(2);
    GINIT(3);
    P2STEP(48,0, br0, br2); P2STEP(49,1, br1, br0);
    P2STEP(50,2, br2, br1); P2STEP(51,3, br0, br2);
    P2STEP(52,4, br1, br0); P2STEP(53,5, br2, br1);
    P2STEP_NS(54,6, br0);   P2STEP_NS(55,7, br1);
    EPI(3);

#undef BLOAD
#undef ISSUE_IN
#undef WRITE_IN
#undef ACCINIT
#undef P1STEP
#undef ACTIVATE
#undef P2BODY
#undef P2STEP
#undef P2STEP_NS
#undef GINIT
#undef EPI
}

extern "C" void kernel_launch(void* const* d_in, const int* in_sizes, int n_in,
                              void* d_out, int out_size, void* d_ws, size_t ws_size,
                              hipStream_t stream)
{
    const float* xin = (const float*)d_in[0];
    const float* hx  = (const float*)d_in[1];
    const float* ts  = (const float*)d_in[2];
    const float* Wb  = (const float*)d_in[3];
    const float* bb  = (const float*)d_in[4];
    const float* W1  = (const float*)d_in[5];
    const float* b1  = (const float*)d_in[6];
    const float* W2  = (const float*)d_in[7];
    const float* b2  = (const float*)d_in[8];
    const float* Wa  = (const float*)d_in[9];
    const float* ba  = (const float*)d_in[10];
    const float* Wt  = (const float*)d_in[11];
    const float* bt  = (const float*)d_in[12];

    if (ws_size < 360448 * sizeof(unsigned short)) return;
    unsigned short* wpk = (unsigned short*)d_ws;

    prep_pack<<<1408, 256, 0, stream>>>(Wb, W1, W2, Wa, Wt, wpk);
    cfc_fused<<<512, 256, 0, stream>>>(xin, hx, ts, bb, b1, b2, ba, bt, wpk,
                                       (float*)d_out);
}

// Round 17
// 82.468 us; speedup vs baseline: 1.1245x; 1.1245x over previous
//
#include <hip/hip_runtime.h>

typedef float v4f __attribute__((ext_vector_type(4)));
typedef short v8s __attribute__((ext_vector_type(8)));

#define BM 128

__device__ __forceinline__ unsigned short f2bf(float f) {
    union { float f; unsigned u; } v; v.f = f;
    unsigned u = v.u;
    u += 0x7FFFu + ((u >> 16) & 1u);   // round-to-nearest-even
    return (unsigned short)(u >> 16);
}

// pack two f32 -> two bf16 (RNE) in one instruction
__device__ __forceinline__ unsigned cvt_pk_bf16(float lo, float hi) {
    unsigned r;
    asm("v_cvt_pk_bf16_f32 %0, %1, %2" : "=v"(r) : "v"(lo), "v"(hi));
    return r;
}

// shared-LDS sync WITHOUT draining vmcnt: only lgkm (ds ops) must complete;
// in-flight global loads into registers survive the barrier.
#define LDS_BARRIER() do {                                        \
    asm volatile("s_waitcnt lgkmcnt(0)" ::: "memory");            \
    __builtin_amdgcn_s_barrier();                                 \
    __builtin_amdgcn_sched_barrier(0);                            \
} while (0)

#define SB() __builtin_amdgcn_sched_barrier(0)

__device__ __forceinline__ float fast_exp2(float x) {
#if __has_builtin(__builtin_amdgcn_exp2f)
    return __builtin_amdgcn_exp2f(x);
#else
    return exp2f(x);
#endif
}
__device__ __forceinline__ float fast_rcp(float x) {
#if __has_builtin(__builtin_amdgcn_rcpf)
    return __builtin_amdgcn_rcpf(x);
#else
    return 1.0f / x;
#endif
}
__device__ __forceinline__ float fast_tanh(float y) {
    float t = fast_exp2(y * 2.885390081777927f);
    return (t - 1.0f) * fast_rcp(t + 1.0f);
}
__device__ __forceinline__ float fast_sigmoid(float z) {
    float t = fast_exp2(-1.4426950408889634f * z);
    return fast_rcp(1.0f + t);
}

// ---------------------------------------------------------------------------
// Pack 5 weight matrices (fp32 row-major [N][K]) into bf16 MFMA-B-fragment
// order (canonical 16x32 tile: lane = ((k>>3)&3)*16 + (n&15), j = k&7).
// ws layout: Wb(98304) | W1(65536) | W2 | Wa | Wt   (bf16 elems)
// ---------------------------------------------------------------------------
__global__ void prep_pack(const float* __restrict__ Wb, const float* __restrict__ W1,
                          const float* __restrict__ W2, const float* __restrict__ Wa,
                          const float* __restrict__ Wt, unsigned short* __restrict__ ws)
{
    int e = blockIdx.x * 256 + threadIdx.x;
    if (e >= 360448) return;
    const float* src; int K; int base;
    if (e < 98304)       { src = Wb; K = 384; base = 0; }
    else if (e < 163840) { src = W1; K = 256; base = 98304; }
    else if (e < 229376) { src = W2; K = 256; base = 163840; }
    else if (e < 294912) { src = Wa; K = 256; base = 229376; }
    else                 { src = Wt; K = 256; base = 294912; }
    int le   = e - base;
    int j    = le & 7;
    int lane = (le >> 3) & 63;
    int tile = le >> 9;
    int kt   = K >> 5;
    int ks   = tile % kt;
    int nt   = tile / kt;
    int n = nt * 16 + (lane & 15);
    int k = ks * 32 + (lane >> 4) * 8 + j;
    ws[e] = f2bf(src[n * K + k]);
}

// ---------------------------------------------------------------------------
// Fused CfC cell, BM=128 rows/block, 4 waves each owning 64 output cols.
// Phase 1: two half-passes of 64 rows (C-slice = 64 AGPR each); phase 2 uses
// the full C[4][8] (128 AGPR) so each 1KB B-load feeds 32 MFMAs — 2x the
// MFMA:fetch ratio of BM=64 and half the per-block L2 weight traffic.
// ARCH-VGPR DIET (vs R16, which spilled at arch=128+agpr=128=256):
//   - B rotation 2-deep (br0/br1, issue-ahead-1; step ~650cyc >> L2 250cyc)
//   - single input staging buffer sA, reissued right after each WRITE_IN
// Arch ~110 < 128 granule; total ~240 <= 256 at (256,2). Grid 512 = exactly
// 2 blocks/CU, one round. X = 64KB LDS; chunks overlay each half's X region.
// Flat 56 steps: 0..23 phase 1 (2 halves x 6 chunks x 2), 24..55 phase 2.
// ---------------------------------------------------------------------------
__global__ __launch_bounds__(256, 2) void cfc_fused(
    const float* __restrict__ xin, const float* __restrict__ hx,
    const float* __restrict__ ts,
    const float* __restrict__ bb, const float* __restrict__ b1,
    const float* __restrict__ b2, const float* __restrict__ ba,
    const float* __restrict__ bt,
    const unsigned short* __restrict__ wpk,
    float* __restrict__ out)
{
    __shared__ unsigned short lds[32768];   // 64 KB: X tiles (mt2,ks) 8x8 x 1KB
    const int tid  = threadIdx.x;
    const int lane = tid & 63;
    const int w    = tid >> 6;        // wave id = output-col group (64 cols)
    const int row0 = blockIdx.x * BM;

    v8s br0[4], br1[4];               // 2-deep B rotation (32 VGPR)
    v4f C[4][8];                      // unified accumulator (128 AGPR in ph2)

// load step-S weight tile (4 x 16B/lane, coalesced) into DST regs
#define BLOAD(S, DST) do {                                                    \
    _Pragma("unroll")                                                         \
    for (int i = 0; i < 4; ++i) {                                             \
        size_t goff;                                                          \
        if ((S) < 24) {                                                       \
            goff = (size_t)((w * 4 + i) * 12 + ((S) % 12)) * 512;             \
        } else {                                                              \
            int s2_ = (S) - 24, g_ = s2_ >> 3, ks_ = s2_ & 7;                 \
            goff = 98304u + (size_t)i * 65536                                 \
                 + (size_t)((w * 4 + g_) * 8 + ks_) * 512;                    \
        }                                                                     \
        DST[i] = *reinterpret_cast<const v8s*>(wpk + goff + (size_t)lane * 8);\
    }                                                                         \
} while (0)

// 64-row x 64-col input chunk: 1024 v4f, 4 per thread
#define ISSUE_IN(SRC, LD, BUF) do {                                           \
    _Pragma("unroll")                                                         \
    for (int it = 0; it < 4; ++it) {                                          \
        int i_ = tid + it * 256; int r_ = i_ >> 4; int c4_ = i_ & 15;         \
        BUF[it] = *(reinterpret_cast<const v4f*>((SRC) + (size_t)r_ * (LD)) + c4_); \
    }                                                                         \
} while (0)

#define WRITE_IN(BUF, CB) do {                                                \
    _Pragma("unroll")                                                         \
    for (int it = 0; it < 4; ++it) {                                          \
        int i_ = tid + it * 256; int r_ = i_ >> 4; int c4_ = i_ & 15;         \
        uint2 pk_;                                                            \
        pk_.x = cvt_pk_bf16(BUF[it][0], BUF[it][1]);                          \
        pk_.y = cvt_pk_bf16(BUF[it][2], BUF[it][3]);                          \
        int idx_ = (((r_ >> 4) * 2 + (c4_ >> 3)) * 64 + ((c4_ >> 1) & 3) * 16 \
                    + (r_ & 15)) * 8 + (c4_ & 1) * 4;                         \
        *reinterpret_cast<uint2*>(&lds[(CB) + idx_]) = pk_;                   \
    }                                                                         \
} while (0)

// accumulator init for half H (bias bb broadcast)
#define ACCINIT(H) do {                                                       \
    _Pragma("unroll")                                                         \
    for (int nt = 0; nt < 4; ++nt) {                                          \
        float bv_ = bb[w * 64 + nt * 16 + (lane & 15)];                       \
        v4f bq_ = {bv_, bv_, bv_, bv_};                                       \
        _Pragma("unroll")                                                     \
        for (int mt = 0; mt < 4; ++mt) C[nt][(H)*4 + mt] = bq_;               \
    }                                                                         \
} while (0)

// phase-1 step (half H): A from chunk LDS at CB=H*16384, B from CUR regs
#define P1STEP(S, H, CUR, PRE) do {                                           \
    BLOAD((S) + 1, PRE);                                                      \
    v8s aa_[4];                                                               \
    _Pragma("unroll")                                                         \
    for (int mt = 0; mt < 4; ++mt)                                            \
        aa_[mt] = *reinterpret_cast<const v8s*>(                              \
                      &lds[(H)*16384 + ((mt * 2 + ((S) & 1)) * 64 + lane) * 8]); \
    __builtin_amdgcn_s_setprio(1);                                            \
    _Pragma("unroll")                                                         \
    for (int nt = 0; nt < 4; ++nt)                                            \
        _Pragma("unroll")                                                     \
        for (int mt = 0; mt < 4; ++mt)                                        \
            C[nt][(H)*4 + mt] = __builtin_amdgcn_mfma_f32_16x16x32_bf16(      \
                              aa_[mt], CUR[nt], C[nt][(H)*4 + mt], 0, 0, 0);  \
    __builtin_amdgcn_s_setprio(0);                                            \
    SB();                                                                     \
} while (0)

// activation for half H: C[nt][H*4+mt] -> X tiles mt2 = H*4+mt
#define ACTIVATE(H) do {                                                      \
    _Pragma("unroll")                                                         \
    for (int nt = 0; nt < 4; ++nt)                                            \
        _Pragma("unroll")                                                     \
        for (int mt = 0; mt < 4; ++mt)                                        \
            _Pragma("unroll")                                                 \
            for (int r = 0; r < 4; ++r) {                                     \
                float xv_ = 1.7159f * fast_tanh(0.666f * C[nt][(H)*4+mt][r]); \
                int idx_ = ((((H)*4+mt)*8 + w*2 + (nt >> 1)) * 64             \
                           + ((nt & 1)*2 + ((lane >> 3) & 1)) * 16            \
                           + (lane >> 4)*4 + r) * 8 + (lane & 7);             \
                lds[idx_] = f2bf(xv_);                                        \
            }                                                                 \
} while (0)

// phase-2 step: 8 row-tiles, A-reads split in halves so the 2nd half's LDS
// latency hides under the 1st MFMA cluster; B (CUR) feeds all 32 MFMAs.
#define P2BODY(KS, CUR) do {                                                  \
    v8s aa_[4];                                                               \
    _Pragma("unroll")                                                         \
    for (int mt = 0; mt < 4; ++mt)                                            \
        aa_[mt] = *reinterpret_cast<const v8s*>(                              \
                      &lds[((mt * 8 + (KS)) * 64 + lane) * 8]);               \
    __builtin_amdgcn_s_setprio(1);                                            \
    _Pragma("unroll")                                                         \
    for (int mat = 0; mat < 4; ++mat)                                         \
        _Pragma("unroll")                                                     \
        for (int mt = 0; mt < 4; ++mt)                                        \
            C[mat][mt] = __builtin_amdgcn_mfma_f32_16x16x32_bf16(             \
                              aa_[mt], CUR[mat], C[mat][mt], 0, 0, 0);        \
    __builtin_amdgcn_s_setprio(0);                                            \
    v8s ab_[4];                                                               \
    _Pragma("unroll")                                                         \
    for (int mt = 0; mt < 4; ++mt)                                            \
        ab_[mt] = *reinterpret_cast<const v8s*>(                              \
                      &lds[(((mt + 4) * 8 + (KS)) * 64 + lane) * 8]);         \
    __builtin_amdgcn_s_setprio(1);                                            \
    _Pragma("unroll")                                                         \
    for (int mat = 0; mat < 4; ++mat)                                         \
        _Pragma("unroll")                                                     \
        for (int mt = 0; mt < 4; ++mt)                                        \
            C[mat][4 + mt] = __builtin_amdgcn_mfma_f32_16x16x32_bf16(         \
                              ab_[mt], CUR[mat], C[mat][4 + mt], 0, 0, 0);    \
    __builtin_amdgcn_s_setprio(0);                                            \
    SB();                                                                     \
} while (0)

#define P2STEP(S, KS, CUR, PRE) do { BLOAD((S) + 1, PRE); P2BODY(KS, CUR); } while (0)
#define P2STEP_NS(S, KS, CUR)   do { P2BODY(KS, CUR); } while (0)

#define GINIT(G) do {                                                         \
    const int n_ = w * 64 + (G) * 16 + (lane & 15);                           \
    float v1_ = b1[n_], v2_ = b2[n_], va_ = ba[n_], vt_ = bt[n_];             \
    v4f q1_ = {v1_,v1_,v1_,v1_}, q2_ = {v2_,v2_,v2_,v2_};                     \
    v4f qa_ = {va_,va_,va_,va_}, qt_ = {vt_,vt_,vt_,vt_};                     \
    _Pragma("unroll")                                                         \
    for (int mt = 0; mt < 8; ++mt) {                                          \
        C[0][mt] = q1_; C[1][mt] = q2_; C[2][mt] = qa_; C[3][mt] = qt_;       \
    }                                                                         \
} while (0)

#define EPI(G) do {                                                           \
    const int n_ = w * 64 + (G) * 16 + (lane & 15);                           \
    _Pragma("unroll")                                                         \
    for (int mt = 0; mt < 8; ++mt) {                                          \
        int rowb_ = row0 + mt * 16 + ((lane >> 4) << 2);                      \
        v4f tsv_ = *reinterpret_cast<const v4f*>(&ts[rowb_]);                 \
        _Pragma("unroll")                                                     \
        for (int r = 0; r < 4; ++r) {                                         \
            float ff1_ = fast_tanh(C[0][mt][r]);                              \
            float ff2_ = fast_tanh(C[1][mt][r]);                              \
            float ti_  = fast_sigmoid(C[2][mt][r] * tsv_[r] + C[3][mt][r]);   \
            out[(size_t)(rowb_ + r) * 256 + n_] = ff1_ + ti_ * (ff2_ - ff1_); \
        }                                                                     \
    }                                                                         \
} while (0)

    v4f sA[4];                        // single staging buffer (16 VGPR)
    const size_t r0 = (size_t)row0, r1 = (size_t)row0 + 64;

    // ---------------- phase 1, half 0 (rows row0..row0+63) ------------------
    ISSUE_IN(xin + r0 * 128, 128, sA);
    BLOAD(0, br0);
    ACCINIT(0);
    WRITE_IN(sA, 0); ISSUE_IN(xin + r0 * 128 + 64, 128, sA);
    LDS_BARRIER();
    P1STEP(0,0, br0, br1); P1STEP(1,0, br1, br0);
    LDS_BARRIER();
    WRITE_IN(sA, 0); ISSUE_IN(hx + r0 * 256, 256, sA);
    LDS_BARRIER();
    P1STEP(2,0, br0, br1); P1STEP(3,0, br1, br0);
    LDS_BARRIER();
    WRITE_IN(sA, 0); ISSUE_IN(hx + r0 * 256 + 64, 256, sA);
    LDS_BARRIER();
    P1STEP(4,0, br0, br1); P1STEP(5,0, br1, br0);
    LDS_BARRIER();
    WRITE_IN(sA, 0); ISSUE_IN(hx + r0 * 256 + 128, 256, sA);
    LDS_BARRIER();
    P1STEP(6,0, br0, br1); P1STEP(7,0, br1, br0);
    LDS_BARRIER();
    WRITE_IN(sA, 0); ISSUE_IN(hx + r0 * 256 + 192, 256, sA);
    LDS_BARRIER();
    P1STEP(8,0, br0, br1); P1STEP(9,0, br1, br0);
    LDS_BARRIER();
    WRITE_IN(sA, 0); ISSUE_IN(xin + r1 * 128, 128, sA);      // half-1 chunk 0
    LDS_BARRIER();
    P1STEP(10,0, br0, br1); P1STEP(11,0, br1, br0);
    LDS_BARRIER();                  // all waves done reading half-0 chunks
    ACTIVATE(0);                    // C[.][0..3] -> X[0,16K) elems
    ACCINIT(1);
    WRITE_IN(sA, 16384); ISSUE_IN(xin + r1 * 128 + 64, 128, sA);
    LDS_BARRIER();

    // ---------------- phase 1, half 1 (rows row0+64..row0+127) --------------
    P1STEP(12,1, br0, br1); P1STEP(13,1, br1, br0);
    LDS_BARRIER();
    WRITE_IN(sA, 16384); ISSUE_IN(hx + r1 * 256, 256, sA);
    LDS_BARRIER();
    P1STEP(14,1, br0, br1); P1STEP(15,1, br1, br0);
    LDS_BARRIER();
    WRITE_IN(sA, 16384); ISSUE_IN(hx + r1 * 256 + 64, 256, sA);
    LDS_BARRIER();
    P1STEP(16,1, br0, br1); P1STEP(17,1, br1, br0);
    LDS_BARRIER();
    WRITE_IN(sA, 16384); ISSUE_IN(hx + r1 * 256 + 128, 256, sA);
    LDS_BARRIER();
    P1STEP(18,1, br0, br1); P1STEP(19,1, br1, br0);
    LDS_BARRIER();
    WRITE_IN(sA, 16384); ISSUE_IN(hx + r1 * 256 + 192, 256, sA);
    LDS_BARRIER();
    P1STEP(20,1, br0, br1); P1STEP(21,1, br1, br0);
    LDS_BARRIER();
    WRITE_IN(sA, 16384);
    LDS_BARRIER();
    P1STEP(22,1, br0, br1); P1STEP(23,1, br1, br0);
    LDS_BARRIER();                  // all waves done reading half-1 chunks
    ACTIVATE(1);                    // C[.][4..7] -> X[16K,32K) elems
    LDS_BARRIER();                  // X fully visible

    // ---------------- phase 2: 4 GEMMs over X + fused epilogue --------------
    GINIT(0);
    P2STEP(24,0, br0, br1); P2STEP(25,1, br1, br0);
    P2STEP(26,2, br0, br1); P2STEP(27,3, br1, br0);
    P2STEP(28,4, br0, br1); P2STEP(29,5, br1, br0);
    P2STEP(30,6, br0, br1); P2STEP(31,7, br1, br0);
    EPI(0);
    GINIT(1);
    P2STEP(32,0, br0, br1); P2STEP(33,1, br1, br0);
    P2STEP(34,2, br0, br1); P2STEP(35,3, br1, br0);
    P2STEP(36,4, br0, br1); P2STEP(37,5, br1, br0);
    P2STEP(38,6, br0, br1); P2STEP(39,7, br1, br0);
    EPI(1);
    GINIT(2);
    P2STEP(40,0, br0, br1); P2STEP(41,1, br1, br0);
    P2STEP(42,2, br0, br1); P2STEP(43,3, br1, br0);
    P2STEP(44,4, br0, br1); P2STEP(45,5, br1, br0);
    P2STEP(46,6, br0, br1); P2STEP(47,7, br1, br0);
    EPI(2);
    GINIT(3);
    P2STEP(48,0, br0, br1); P2STEP(49,1, br1, br0);
    P2STEP(50,2, br0, br1); P2STEP(51,3, br1, br0);
    P2STEP(52,4, br0, br1); P2STEP(53,5, br1, br0);
    P2STEP(54,6, br0, br1); P2STEP_NS(55,7, br1);
    EPI(3);

#undef BLOAD
#undef ISSUE_IN
#undef WRITE_IN
#undef ACCINIT
#undef P1STEP
#undef ACTIVATE
#undef P2BODY
#undef P2STEP
#undef P2STEP_NS
#undef GINIT
#undef EPI
}

extern "C" void kernel_launch(void* const* d_in, const int* in_sizes, int n_in,
                              void* d_out, int out_size, void* d_ws, size_t ws_size,
                              hipStream_t stream)
{
    const float* xin = (const float*)d_in[0];
    const float* hx  = (const float*)d_in[1];
    const float* ts  = (const float*)d_in[2];
    const float* Wb  = (const float*)d_in[3];
    const float* bb  = (const float*)d_in[4];
    const float* W1  = (const float*)d_in[5];
    const float* b1  = (const float*)d_in[6];
    const float* W2  = (const float*)d_in[7];
    const float* b2  = (const float*)d_in[8];
    const float* Wa  = (const float*)d_in[9];
    const float* ba  = (const float*)d_in[10];
    const float* Wt  = (const float*)d_in[11];
    const float* bt  = (const float*)d_in[12];

    if (ws_size < 360448 * sizeof(unsigned short)) return;
    unsigned short* wpk = (unsigned short*)d_ws;

    prep_pack<<<1408, 256, 0, stream>>>(Wb, W1, W2, Wa, Wt, wpk);
    cfc_fused<<<512, 256, 0, stream>>>(xin, hx, ts, bb, b1, b2, ba, bt, wpk,
                                       (float*)d_out);
}